// Round 11
// baseline (470.681 us; speedup 1.0000x reference)
//
#include <hip/hip_runtime.h>
#include <hip/hip_bf16.h>
#include <stdint.h>

#define N_EXPERTS 8
#define DIM 2048
#define INTER 1408
#define NGU (2*INTER)          // 2816
#define TOK_E 2048             // tokens per expert
#define TOTAL_TOKENS 16384

typedef __attribute__((ext_vector_type(8))) short short8;
typedef __attribute__((ext_vector_type(16))) float f32x16;

__device__ __forceinline__ unsigned short f2bf(float f) {
    union { float f; unsigned u; } v; v.f = f;
    unsigned r = v.u + 0x7FFF + ((v.u >> 16) & 1);   // RNE
    return (unsigned short)(r >> 16);
}

#define GLOAD16(G, L) __builtin_amdgcn_global_load_lds( \
    (const __attribute__((address_space(1))) void*)(G), \
    (__attribute__((address_space(3))) void*)(L), 16, 0, 0)

// ---------------- prep kernels (R5/R9 form, verified) ----------------

__global__ void convert_x(const float* __restrict__ in, unsigned short* __restrict__ out, int n8) {
    int i = blockIdx.x * blockDim.x + threadIdx.x;
    int stride = gridDim.x * blockDim.x;
    for (; i < n8; i += stride) {
        const float4* p = (const float4*)(in + (size_t)i * 8);
        float4 v0 = p[0], v1 = p[1];
        union { unsigned short u[8]; uint4 q; } o;
        o.u[0]=f2bf(v0.x); o.u[1]=f2bf(v0.y); o.u[2]=f2bf(v0.z); o.u[3]=f2bf(v0.w);
        o.u[4]=f2bf(v1.x); o.u[5]=f2bf(v1.y); o.u[6]=f2bf(v1.z); o.u[7]=f2bf(v1.w);
        *(uint4*)(out + (size_t)i * 8) = o.q;
    }
}

// in: [E][K][N] fp32 -> out: [E][N][K] bf16, 128(K)x32(N) per block, 8B stores.
// permute (R1 form, validated): 64-row groups {32 gate, 32 up} per 32 act cols:
//   a = c>>1 -> B' row = ((a>>5)<<6) + (a&31) + ((c&1)<<5)
__global__ __launch_bounds__(256)
void transpose_convert(const float* __restrict__ in, unsigned short* __restrict__ out,
                       int K, int N, int permute) {
    __shared__ float tile[32][129];
    const int n0 = blockIdx.x * 32, k0 = blockIdx.y * 128;
    const size_t ein  = (size_t)blockIdx.z * K * N;
    const size_t eout = (size_t)blockIdx.z * N * K;
    const int tc = threadIdx.x & 31;
    const int tr = threadIdx.x >> 5;
    #pragma unroll
    for (int i = 0; i < 16; ++i) {
        int k = tr + i * 8;
        tile[tc][k] = in[ein + (size_t)(k0 + k) * N + n0 + tc];
    }
    __syncthreads();
    const int kg = threadIdx.x & 31;
    const int r0 = threadIdx.x >> 5;
    #pragma unroll
    for (int i = 0; i < 4; ++i) {
        int r = r0 + i * 8;
        int c = n0 + r;
        int dr = c;
        if (permute) {
            int a = c >> 1;
            dr = ((a >> 5) << 6) + (a & 31) + ((c & 1) << 5);
        }
        union { unsigned short u[4]; uint2 q; } o;
        #pragma unroll
        for (int j = 0; j < 4; ++j) o.u[j] = f2bf(tile[r][kg * 4 + j]);
        *(uint2*)(out + eout + (size_t)dr * K + k0 + kg * 4) = o.q;
    }
}

// ---------------- 256x256xBK64 GEMM, 2-buffer, 8-phase pipeline (R11) --------
// R10/R7 skeleton + ledger byte-identical. R11 delta: 32x32x16 MFMA (2382 vs
// 2075 TF ubench; MFMA leg of the serial window 620->515 cyc). Same LDS bytes,
// same frag VGPR count, same acc total (8 x f32x16 = 128).
// Layouts: A/B operand row/col = lane&31, k = s*16 + (lane>>5)*8 + j.
// C/D: col = lane&31, row = (r&3) + 8*(r>>2) + 4*(lane>>5), r in [0,16).
// Wave cols = wn*64 + qn*32 + (lane&31) -> GEGLU lane-local with R1 permute.
// Swizzle: slot = (s*2 + (lane>>5)) ^ (lane&7) (2 lanes/slot per 16-lane group = free).
// Window: DS;STG;SB0;lgkm;END;SB0;barrier;setprio;MFMA;setprio;SB0.
// Stage rotation: P1:b1.Ah1(kt+1) P2:b0.Ah0(kt+2) P3:b0.Bh0 P4:b0.Bh1 P5:b0.Ah1
//                 P6:b1.Ah0(kt+3) P7:b1.Bh0 P8:b1.Bh1.   vmcnt(6) @P4 and @P8.

#define SB0 __builtin_amdgcn_sched_barrier(0)
#define VMC(N_) asm volatile("s_waitcnt vmcnt(" #N_ ")" ::: "memory")
#define LGK8 asm volatile("s_waitcnt lgkmcnt(8)" ::: "memory")

#define GEMM_PROLOG(LDKC) \
    const int t = threadIdx.x; \
    const int lane = t & 63, wid = t >> 6; \
    const int wm = wid >> 2, wn = wid & 3;            /* 2M x 4N wave grid */ \
    const int row31 = lane & 31, h5 = lane >> 5; \
    const int so0 = ((0 * 2 + h5) ^ (lane & 7)) * 8; \
    const int so1 = ((1 * 2 + h5) ^ (lane & 7)) * 8; \
    const int so2 = ((2 * 2 + h5) ^ (lane & 7)) * 8; \
    const int so3 = ((3 * 2 + h5) ^ (lane & 7)) * 8; \
    const size_t goff = (size_t)(t >> 3) * (LDKC) + (size_t)(((t & 7) ^ ((t >> 3) & 7)) * 8); \
    const int ldsw = wid * 512 + lane * 8;

#define STGA(LDKC, bb_, h_, kt_) do { \
    const unsigned short* g_ = gA + (size_t)(h_) * 128 * (LDKC) + (size_t)(kt_) * 64 + goff; \
    unsigned short* l_ = sA + (bb_) * 16384 + (h_) * 8192 + ldsw; \
    GLOAD16(g_, l_); GLOAD16(g_ + (size_t)64 * (LDKC), l_ + 4096); \
} while (0)

#define STGB(LDKC, bb_, h_, kt_) do { \
    const unsigned short* g_ = gB + (size_t)(h_) * 128 * (LDKC) + (size_t)(kt_) * 64 + goff; \
    unsigned short* l_ = sB + (bb_) * 16384 + (h_) * 8192 + ldsw; \
    GLOAD16(g_, l_); GLOAD16(g_ + (size_t)64 * (LDKC), l_ + 4096); \
} while (0)

// A frags for quadrant qm: m in {0,1} (32-row frags), s in {0..3} (16-k steps)
#define DSA2(bb_, qm_) do { \
    const unsigned short* p_ = &sA[(bb_) * 16384 + ((qm_) * 128 + wm * 64 + row31) * 64]; \
    a[0][0] = *(const short8*)(p_ + so0);        a[0][1] = *(const short8*)(p_ + so1); \
    a[0][2] = *(const short8*)(p_ + so2);        a[0][3] = *(const short8*)(p_ + so3); \
    a[1][0] = *(const short8*)(p_ + 2048 + so0); a[1][1] = *(const short8*)(p_ + 2048 + so1); \
    a[1][2] = *(const short8*)(p_ + 2048 + so2); a[1][3] = *(const short8*)(p_ + 2048 + so3); \
} while (0)

// B frags for quadrant qn: one 32-col frag, s in {0..3}
#define DSB2(bb_, qn_, R_) do { \
    const unsigned short* p_ = &sB[(bb_) * 16384 + (wn * 64 + (qn_) * 32 + row31) * 64]; \
    R_[0] = *(const short8*)(p_ + so0); R_[1] = *(const short8*)(p_ + so1); \
    R_[2] = *(const short8*)(p_ + so2); R_[3] = *(const short8*)(p_ + so3); \
} while (0)

// 8 MFMA per window (s-outer: dependent writes of one acc reg are 2 apart)
#define QMF(qm_, qn_, B_) do { \
    _Pragma("unroll") for (int s_ = 0; s_ < 4; ++s_) { \
        _Pragma("unroll") for (int m_ = 0; m_ < 2; ++m_) { \
            acc[qm_][qn_][m_] = __builtin_amdgcn_mfma_f32_32x32x16_bf16(a[m_][s_], B_[s_], acc[qm_][qn_][m_], 0, 0, 0); \
        } } \
} while (0)

// one barrier per phase; lgkm0 + vmc (ENDOPS) BEFORE it; MFMA after it.
#define PH(DSOPS, STGOPS, MFOPS, ENDOPS) do { \
    DSOPS; \
    STGOPS; \
    SB0; \
    asm volatile("s_waitcnt lgkmcnt(0)" ::: "memory"); \
    ENDOPS; \
    SB0; \
    __builtin_amdgcn_s_barrier(); \
    __builtin_amdgcn_s_setprio(1); \
    MFOPS; \
    __builtin_amdgcn_s_setprio(0); \
    SB0; \
} while (0)

#define ITER8(LDKC, kt0_, SG2, SG3, SG4, SG5, SG6, SG7, SG8, E4, E8) \
    PH(DSA2(0,0); DSB2(0,0,bq0); LGK8, STGA(LDKC,1,1,(kt0_)+1), QMF(0,0,bq0), ); \
    PH(DSB2(0,1,bq1),            SG2,                     QMF(0,1,bq1), ); \
    PH(DSA2(0,1),                SG3,                     QMF(1,0,bq0), ); \
    PH(,                         SG4,                     QMF(1,1,bq1), E4); \
    PH(DSA2(1,0); DSB2(1,0,bq0); LGK8, SG5,               QMF(0,0,bq0), ); \
    PH(DSB2(1,1,bq1),            SG6,                     QMF(0,1,bq1), ); \
    PH(DSA2(1,1),                SG7,                     QMF(1,0,bq0), ); \
    PH(,                         SG8,                     QMF(1,1,bq1), E8);

#define GEMM_PIPE(LDKC, NI_) \
    short8 a[2][4], bq0[4], bq1[4]; \
    f32x16 acc[2][2][2]; \
    _Pragma("unroll") for (int q_ = 0; q_ < 2; ++q_) \
    _Pragma("unroll") for (int r_ = 0; r_ < 2; ++r_) \
    _Pragma("unroll") for (int m_ = 0; m_ < 2; ++m_) acc[q_][r_][m_] = (f32x16)0.0f; \
    /* prologue: slots P2..P8 -> b0.Ah0 b0.Bh0 b0.Bh1 b0.Ah1 b1.Ah0 b1.Bh0 b1.Bh1 */ \
    STGA(LDKC,0,0,0); STGB(LDKC,0,0,0); STGB(LDKC,0,1,0); STGA(LDKC,0,1,0); \
    STGA(LDKC,1,0,1); STGB(LDKC,1,0,1); STGB(LDKC,1,1,1); \
    VMC(6); \
    __builtin_amdgcn_s_barrier(); \
    for (int it = 0; it < (NI_) - 1; ++it) { \
        const int kt0 = 2 * it; \
        ITER8(LDKC, kt0, \
              STGA(LDKC,0,0,kt0+2), STGB(LDKC,0,0,kt0+2), STGB(LDKC,0,1,kt0+2), STGA(LDKC,0,1,kt0+2), \
              STGA(LDKC,1,0,kt0+3), STGB(LDKC,1,0,kt0+3), STGB(LDKC,1,1,kt0+3), \
              VMC(6), VMC(6)) \
    } \
    { \
        const int kt0 = 2 * ((NI_) - 1); \
        ITER8(LDKC, kt0, , , , , , , , VMC(0), ) \
    }

// ---------------- GEMM 1: x @ gate_up^T (permuted) + GEGLU, bf16 act out ----------------

__global__ __launch_bounds__(512, 2)
void gemm_gu(const unsigned short* __restrict__ A,    // x bf16 [16384][2048]
             const unsigned short* __restrict__ Bt,   // [E][2816][2048] permuted-transposed
             const float* __restrict__ probs,         // [16384]
             unsigned short* __restrict__ act) {      // [16384][1408] bf16
    __shared__ unsigned short sA[2 * 16384];
    __shared__ unsigned short sB[2 * 16384];
    GEMM_PROLOG(DIM)
    const int bid = blockIdx.x;           // 704 = 8 experts * (8 tm * 11 tn)
    const int e = bid & 7;                // expert per XCD (T1)
    const int local = bid >> 3;           // [0, 88), tm-fastest
    const int tm = local & 7;
    const int tn = local >> 3;            // [0, 11)
    const unsigned short* gA = A  + (size_t)(e * TOK_E + tm * 256) * DIM;
    const unsigned short* gB = Bt + (size_t)e * NGU * DIM + (size_t)(tn * 256) * DIM;

    GEMM_PIPE(DIM, 16)   // K = 2048 = 32 tiles of 64 = 16 iterations

    // epilogue: wave group = tn*4 + wn; act col = group*32 + row31
    // gate = acc[qm][0][m], up = acc[qm][1][m] (same lane, same reg) — R1 permute
    const int acol = tn * 128 + wn * 32 + row31;
    #pragma unroll
    for (int qm = 0; qm < 2; ++qm) {
        #pragma unroll
        for (int m = 0; m < 2; ++m) {
            const int rbase = e * TOK_E + tm * 256 + qm * 128 + wm * 64 + m * 32 + 4 * h5;
            #pragma unroll
            for (int r = 0; r < 16; ++r) {
                const int row = rbase + (r & 3) + 8 * (r >> 2);
                float p = probs[row];
                float g = fminf(acc[qm][0][m][r], 7.0f);
                float u = fminf(fmaxf(acc[qm][1][m][r], -7.0f), 7.0f);
                float glu = g / (1.0f + __expf(-1.702f * g));
                float rv = glu * (u + 1.0f) * p;
                act[(size_t)row * INTER + acol] = f2bf(rv);
            }
        }
    }
}

// ---------------- GEMM 2: act @ down^T, fp32 out ----------------

__global__ __launch_bounds__(512, 2)
void gemm_down(const unsigned short* __restrict__ A,   // act bf16 [16384][1408]
               const unsigned short* __restrict__ Bt,  // [E][2048][1408]
               float* __restrict__ out) {               // [16384][2048] fp32
    __shared__ unsigned short sA[2 * 16384];
    __shared__ unsigned short sB[2 * 16384];
    GEMM_PROLOG(INTER)
    const int bid = blockIdx.x;           // 512 = 8 experts * (8 tm * 8 tn)
    const int e = bid & 7;
    const int local = bid >> 3;           // [0, 64), tm-fastest
    const int tm = local & 7;
    const int tn = local >> 3;            // [0, 8)
    const unsigned short* gA = A  + (size_t)(e * TOK_E + tm * 256) * INTER;
    const unsigned short* gB = Bt + (size_t)e * DIM * INTER + (size_t)(tn * 256) * INTER;

    GEMM_PIPE(INTER, 11)   // K = 1408 = 22 tiles of 64 = 11 iterations

    #pragma unroll
    for (int qm = 0; qm < 2; ++qm) {
        #pragma unroll
        for (int qn = 0; qn < 2; ++qn) {
            const int col = tn * 256 + wn * 64 + qn * 32 + row31;
            #pragma unroll
            for (int m = 0; m < 2; ++m) {
                const int rbase = e * TOK_E + tm * 256 + qm * 128 + wm * 64 + m * 32 + 4 * h5;
                #pragma unroll
                for (int r = 0; r < 16; ++r) {
                    const int row = rbase + (r & 3) + 8 * (r >> 2);
                    out[(size_t)row * DIM + col] = acc[qm][qn][m][r];
                }
            }
        }
    }
}

// ---------------- launcher ----------------

extern "C" void kernel_launch(void* const* d_in, const int* in_sizes, int n_in,
                              void* d_out, int out_size, void* d_ws, size_t ws_size,
                              hipStream_t stream) {
    const float* x     = (const float*)d_in[0];
    const float* probs = (const float*)d_in[1];
    const float* gup   = (const float*)d_in[2];
    const float* dwn   = (const float*)d_in[3];
    float* out = (float*)d_out;

    char* ws = (char*)d_ws;
    const size_t SZ_XB  = (size_t)TOTAL_TOKENS * DIM * 2;      // 67,108,864
    const size_t SZ_GUB = (size_t)N_EXPERTS * NGU * DIM * 2;   // 92,274,688
    const size_t SZ_DWB = (size_t)N_EXPERTS * DIM * INTER * 2; // 46,137,344
    unsigned short* xb   = (unsigned short*)(ws);
    unsigned short* gub  = (unsigned short*)(ws + SZ_XB);
    unsigned short* dwb  = (unsigned short*)(ws + SZ_XB + SZ_GUB);
    unsigned short* actb = (unsigned short*)(ws + SZ_XB + SZ_GUB + SZ_DWB);

    convert_x<<<2048, 256, 0, stream>>>(x, xb, TOTAL_TOKENS * DIM / 8);

    dim3 tg1(NGU / 32, DIM / 128, N_EXPERTS);     // (88, 16, 8)
    transpose_convert<<<tg1, 256, 0, stream>>>(gup, gub, DIM, NGU, 1);
    dim3 tg2(DIM / 32, INTER / 128, N_EXPERTS);   // (64, 11, 8)
    transpose_convert<<<tg2, 256, 0, stream>>>(dwn, dwb, INTER, DIM, 0);

    gemm_gu<<<704, 512, 0, stream>>>(xb, gub, probs, actb);
    gemm_down<<<512, 512, 0, stream>>>(actb, dwb, out);
}